// Round 1
// baseline (836.567 us; speedup 1.0000x reference)
//
#include <hip/hip_runtime.h>

// ShawRelativePositionalEmbedding on MI355X (gfx950) — v2: swapped-operand
// MFMA + LDS-staged aligned float4 epilogue.
//
// out[bh][n][r] = sum_d (q[bh][n][d]*0.125) * E[n - r + 2048][d]
//   q:   [32, 2048, 64] fp32   (b*h flattened; 0.125 folded into q->bf16, exact)
//   E:   [4097, 64]     fp32
//   out: [32, 2048, 2048] fp32  (537 MB -> write-bound, ~90us floor)
//
// Diagonal substitution u = n - r + 2048: banded GEMM T[u][n] = E[u,:].Q[n,:]
// (operands SWAPPED vs v1 so D's row-dim is u). Per lane the 4 acc values are
// 4 consecutive u for one n -> one ds_write_b128 into a [64n][68] LDS tile.
// Epilogue then streams the tile out row-major with 16B-ALIGNED float4 stores
// (4 lanes = 64B aligned segment per row); the <=6 misaligned edge dwords per
// row per j are stored scalar, covering each (n,r) exactly once.
// E tile for j+1 is prefetched into registers during compute of j.

#define NSEQ 2048
#define MAXS 2048

typedef short bf16x8 __attribute__((ext_vector_type(8)));  // 8 bf16 in 4 VGPRs
typedef float f32x4  __attribute__((ext_vector_type(4)));

__device__ __forceinline__ short f2bf(float f) {
    union { float f; unsigned u; } v; v.f = f;
    unsigned r = v.u + 0x7fffu + ((v.u >> 16) & 1u);   // round-to-nearest-even
    return (short)(r >> 16);
}

__device__ __forceinline__ bf16x8 cvt8(float4 x, float4 y) {
    bf16x8 f;
    f[0] = f2bf(x.x); f[1] = f2bf(x.y); f[2] = f2bf(x.z); f[3] = f2bf(x.w);
    f[4] = f2bf(y.x); f[5] = f2bf(y.y); f[6] = f2bf(y.z); f[7] = f2bf(y.w);
    return f;
}

__device__ __forceinline__ bf16x8 load_cvt8_scaled(const float* p, float s) {
    float4 x = *(const float4*)(p);
    float4 y = *(const float4*)(p + 4);
    bf16x8 f;
    f[0] = f2bf(s * x.x); f[1] = f2bf(s * x.y); f[2] = f2bf(s * x.z); f[3] = f2bf(s * x.w);
    f[4] = f2bf(s * y.x); f[5] = f2bf(s * y.y); f[6] = f2bf(s * y.z); f[7] = f2bf(s * y.w);
    return f;
}

__global__ __launch_bounds__(256, 4)
void shaw_rel_pos_kernel(const float* __restrict__ q,
                         const float* __restrict__ emb,
                         float* __restrict__ out) {
    // lds[n_loc][u_loc]; stride 68 floats = 272B: 16B-aligned cols, conflict-free b128.
    __shared__ float lds[64][68];

    const int tid  = threadIdx.x;
    const int n0   = blockIdx.x * 64;   // n-tile base (32 tiles)
    const int bh   = blockIdx.y;        // 0..31
    const int wave = tid >> 6;          // 0..3, owns u-subtile [16w, 16w+16)
    const int lane = tid & 63;
    const int l16  = lane & 15;
    const int quad = lane >> 4;

    // ---- Q fragments (B-operand: B[k][col=l16] = Q[n0+s*16+l16][k]), resident.
    // Scale 2^-3 folded in: rne(0.125*q) == 0.125*rne(q) exactly.
    bf16x8 qf[4][2];
#pragma unroll
    for (int s = 0; s < 4; ++s) {
        const float* qp = q + ((size_t)(bh * NSEQ + n0 + s * 16 + l16) * 64 + quad * 8);
#pragma unroll
        for (int kk = 0; kk < 2; ++kk)
            qf[s][kk] = load_cvt8_scaled(qp + kk * 32, 0.125f);
    }

    const int uoff = wave * 16 + l16;   // E row offset within the 64-wide u tile
    float* outb = out + ((size_t)bh * NSEQ) * NSEQ;

    // ---- prefetch E tile j=0 (A-operand: A[m=l16][k] = E[u0+16w+l16][k])
    const float* ep = emb + ((size_t)(n0 + uoff) * 64 + quad * 8);
    float4 ra0 = *(const float4*)(ep);      float4 ra1 = *(const float4*)(ep + 4);
    float4 rb0 = *(const float4*)(ep + 32); float4 rb1 = *(const float4*)(ep + 36);

    for (int j = 0; j < 33; ++j) {
        bf16x8 ef0 = cvt8(ra0, ra1);
        bf16x8 ef1 = cvt8(rb0, rb1);
        if (j < 32) {   // prefetch j+1 (overlaps MFMA + epilogue)
            const float* ep2 = emb + ((size_t)(n0 + (j + 1) * 64 + uoff) * 64 + quad * 8);
            ra0 = *(const float4*)(ep2);      ra1 = *(const float4*)(ep2 + 4);
            rb0 = *(const float4*)(ep2 + 32); rb1 = *(const float4*)(ep2 + 36);
        }

        f32x4 acc[4];
#pragma unroll
        for (int s = 0; s < 4; ++s) {
            acc[s] = (f32x4){0.f, 0.f, 0.f, 0.f};
            acc[s] = __builtin_amdgcn_mfma_f32_16x16x32_bf16(ef0, qf[s][0], acc[s], 0, 0, 0);
            acc[s] = __builtin_amdgcn_mfma_f32_16x16x32_bf16(ef1, qf[s][1], acc[s], 0, 0, 0);
        }

        // D layout: col=l16 -> n = n0+s*16+l16; row=quad*4+t -> u_loc = 16w+4q+t.
        // 4 consecutive u per lane -> one aligned ds_write_b128 per subtile.
        __syncthreads();   // previous epilogue done reading lds
#pragma unroll
        for (int s = 0; s < 4; ++s)
            *reinterpret_cast<f32x4*>(&lds[s * 16 + l16][wave * 16 + quad * 4]) = acc[s];
        __syncthreads();   // tile visible

        // ---- epilogue: 4 threads per output row, aligned float4 stores.
        // Row n covers r in [A-63, A] (clipped), A = 2048 + n_loc - 64j;
        // out[n][r] = lds[n_loc][A - r] (reversed read, forward aligned write).
        const int nloc = tid >> 2;
        const int A    = MAXS + nloc - 64 * j;
        int rlo = A - 63; if (rlo < 0) rlo = 0;
        int rhi = A;      if (rhi > NSEQ - 1) rhi = NSEQ - 1;
        if (rlo <= rhi) {
            float*       orow = outb + (size_t)(n0 + nloc) * NSEQ;
            const float* lrow = &lds[nloc][0];
            const int wfirst = (rlo + 3) & ~3;              // first aligned col >= rlo
            const int d      = rhi + 1 - wfirst;
            const int nw     = d > 0 ? (d >> 2) : 0;        // full aligned windows
            const int k4     = tid & 3;
            for (int w = wfirst + 4 * k4; w < wfirst + 4 * nw; w += 16) {
                float4 v;
                v.x = lrow[A - w];
                v.y = lrow[A - w - 1];
                v.z = lrow[A - w - 2];
                v.w = lrow[A - w - 3];
                *(float4*)(orow + w) = v;                   // 16B-aligned
            }
            if (k4 == 0) {                                  // low edge, <=3 dwords
                const int lo_end = wfirst < rhi + 1 ? wfirst : rhi + 1;
                for (int r = rlo; r < lo_end; ++r) orow[r] = lrow[A - r];
            } else if (k4 == 3) {                           // high edge, <=3 dwords
                for (int r = wfirst + 4 * nw; r <= rhi; ++r) orow[r] = lrow[A - r];
            }
        }
    }
}

extern "C" void kernel_launch(void* const* d_in, const int* in_sizes, int n_in,
                              void* d_out, int out_size, void* d_ws, size_t ws_size,
                              hipStream_t stream) {
    const float* q   = (const float*)d_in[0];
    // d_in[1] = k — unused by the reference forward.
    const float* emb = (const float*)d_in[2];   // [4097, 64]
    float* out = (float*)d_out;                 // [2, 16, 2048, 2048]

    dim3 grid(32, 32);   // x: n-tile, y: bh
    dim3 block(256);
    shaw_rel_pos_kernel<<<grid, block, 0, stream>>>(q, emb, out);
}

// Round 2
// 593.363 us; speedup vs baseline: 1.4099x; 1.4099x over previous
//
#include <hip/hip_runtime.h>

// ShawRelativePositionalEmbedding on MI355X (gfx950) — v3: r-aligned emit via
// triple-buffered, u-flipped LDS tiles; raw lgkmcnt-only barrier (stores stream).
//
// out[bh][n][r] = sum_d (q[bh][n][d]*0.125) * E[n - r + 2048][d]
//   q: [32,2048,64] fp32, E: [4097,64] fp32, out: [32,2048,2048] fp32 (537 MB).
//
// Banded GEMM over u = n - r + 2048 (swapped operands: D rows = u, cols = n).
// Tile j computes u in [n0+64j, n0+64j+64) and stores it u-FLIPPED into LDS
// buffer j%3 (one aligned ds_write_b128 per lane per subtile). At step j>=1 the
// block emits the r-window [2048-64j, 2111-64j] of all 64 rows: with the flip,
// row n's window is two forward-contiguous LDS runs (tiles j, j-1), written as
// perfectly 256B-aligned complete row chunks -> zero HBM write amplification,
// zero bounds checks. Triple buffering => ONE barrier per j; the barrier is raw
// s_waitcnt lgkmcnt(0) + s_barrier, so global stores are never vmcnt-drained.

#define NSEQ 2048
#define MAXS 2048
#define LSTRIDE 196   // 3 halves * 64 + 4 pad (keeps 16B align, spreads banks)

typedef short bf16x8 __attribute__((ext_vector_type(8)));  // 8 bf16 in 4 VGPRs
typedef float f32x4  __attribute__((ext_vector_type(4)));

__device__ __forceinline__ short f2bf(float f) {
    union { float f; unsigned u; } v; v.f = f;
    unsigned r = v.u + 0x7fffu + ((v.u >> 16) & 1u);   // round-to-nearest-even
    return (short)(r >> 16);
}

__device__ __forceinline__ bf16x8 cvt8(float4 x, float4 y) {
    bf16x8 f;
    f[0] = f2bf(x.x); f[1] = f2bf(x.y); f[2] = f2bf(x.z); f[3] = f2bf(x.w);
    f[4] = f2bf(y.x); f[5] = f2bf(y.y); f[6] = f2bf(y.z); f[7] = f2bf(y.w);
    return f;
}

__device__ __forceinline__ bf16x8 load_cvt8_scaled(const float* p, float s) {
    float4 x = *(const float4*)(p);
    float4 y = *(const float4*)(p + 4);
    bf16x8 f;
    f[0] = f2bf(s * x.x); f[1] = f2bf(s * x.y); f[2] = f2bf(s * x.z); f[3] = f2bf(s * x.w);
    f[4] = f2bf(s * y.x); f[5] = f2bf(s * y.y); f[6] = f2bf(s * y.z); f[7] = f2bf(s * y.w);
    return f;
}

__global__ __launch_bounds__(256, 3)
void shaw_rel_pos_kernel(const float* __restrict__ q,
                         const float* __restrict__ emb,
                         float* __restrict__ out) {
    __shared__ float lds[64][LSTRIDE];   // [n_loc][3 u-flipped halves of 64]

    const int tid  = threadIdx.x;
    const int n0   = blockIdx.x * 64;   // n-tile base (32 tiles)
    const int bh   = blockIdx.y;        // 0..31
    const int wave = tid >> 6;          // 0..3, owns u-subtile [16w, 16w+16)
    const int lane = tid & 63;
    const int l16  = lane & 15;
    const int quad = lane >> 4;

    // ---- Q fragments (B-operand: B[k][col=l16] = Q[n0+s*16+l16][k]), resident.
    // Scale 2^-3 folded into the bf16 convert (exact: power-of-two * RNE commute).
    bf16x8 qf[4][2];
#pragma unroll
    for (int s = 0; s < 4; ++s) {
        const float* qp = q + ((size_t)(bh * NSEQ + n0 + s * 16 + l16) * 64 + quad * 8);
#pragma unroll
        for (int kk = 0; kk < 2; ++kk)
            qf[s][kk] = load_cvt8_scaled(qp + kk * 32, 0.125f);
    }

    const int uoff = wave * 16 + l16;        // E row offset within 64-wide u tile
    float* outb = out + ((size_t)bh * NSEQ) * NSEQ;

    // ---- emit-role constants: 4 threads per output row, 16 floats each.
    const int nloc = tid >> 2;               // 0..63
    const int k4   = tid & 3;
    const float* lrow = &lds[nloc][0];
    float* orow0 = outb + (size_t)(n0 + nloc) * NSEQ + 4 * k4;

    // flipped b128 write column base within a half: pos = 63 - (16w+4q+3)
    const int wbase = 60 - 16 * wave - 4 * quad;

    // ---- prefetch E tile j=0 (A-operand: A[m=l16][k] = E[u0+16w+l16][k])
    const float* ep = emb + ((size_t)(n0 + uoff) * 64 + quad * 8);
    float4 ra0 = *(const float4*)(ep);      float4 ra1 = *(const float4*)(ep + 4);
    float4 rb0 = *(const float4*)(ep + 32); float4 rb1 = *(const float4*)(ep + 36);

    int h  = 0;    // (j % 3) * 64
    int hp = 128;  // ((j-1) % 3) * 64  (unused at j=0)

    for (int j = 0; j < 33; ++j) {
        bf16x8 ef0 = cvt8(ra0, ra1);
        bf16x8 ef1 = cvt8(rb0, rb1);
        if (j < 32) {   // prefetch tile j+1 (hides under MFMA + emit)
            const float* ep2 = emb + ((size_t)(n0 + (j + 1) * 64 + uoff) * 64 + quad * 8);
            ra0 = *(const float4*)(ep2);      ra1 = *(const float4*)(ep2 + 4);
            rb0 = *(const float4*)(ep2 + 32); rb1 = *(const float4*)(ep2 + 36);
        }

        f32x4 acc[4];
#pragma unroll
        for (int s = 0; s < 4; ++s) {
            acc[s] = (f32x4){0.f, 0.f, 0.f, 0.f};
            acc[s] = __builtin_amdgcn_mfma_f32_16x16x32_bf16(ef0, qf[s][0], acc[s], 0, 0, 0);
            acc[s] = __builtin_amdgcn_mfma_f32_16x16x32_bf16(ef1, qf[s][1], acc[s], 0, 0, 0);
        }

        // D layout: col=l16 -> n = n0+s*16+l16; row=quad*4+t -> u_loc = 16w+4q+t.
        // Store u-FLIPPED (pos = 63 - u_loc): one aligned ds_write_b128 per s.
#pragma unroll
        for (int s = 0; s < 4; ++s) {
            f32x4 rv = {acc[s][3], acc[s][2], acc[s][1], acc[s][0]};
            *reinterpret_cast<f32x4*>(&lds[s * 16 + l16][h + wbase]) = rv;
        }

        // barrier: LDS visibility only — do NOT drain global stores (no vmcnt).
        asm volatile("s_waitcnt lgkmcnt(0)" ::: "memory");
        __builtin_amdgcn_s_barrier();
        asm volatile("" ::: "memory");

        if (j >= 1) {
            // r-window [R0, R0+63], R0 = 2048 - 64j. Row n, col c = R0 + cb:
            //   c <= nloc: tile j   at pos 63-nloc+cb   (forward run)
            //   c >  nloc: tile j-1 at pos cb-nloc-1    (forward run)
            const float* pA = lrow + (h  + 63 - nloc);
            const float* pB = lrow + (hp - nloc - 1);
            float* od = orow0 + (NSEQ - 64 * j);
#pragma unroll
            for (int i = 0; i < 4; ++i) {
                const int cb = 16 * i + 4 * k4;
                float4 v;
                v.x = (cb + 0 <= nloc ? pA : pB)[cb + 0];
                v.y = (cb + 1 <= nloc ? pA : pB)[cb + 1];
                v.z = (cb + 2 <= nloc ? pA : pB)[cb + 2];
                v.w = (cb + 3 <= nloc ? pA : pB)[cb + 3];
                *(float4*)(od + 16 * i) = v;      // 256B-aligned complete chunks
            }
        }

        hp = h;
        h += 64; if (h == 192) h = 0;   // (j+1) % 3
    }
}

extern "C" void kernel_launch(void* const* d_in, const int* in_sizes, int n_in,
                              void* d_out, int out_size, void* d_ws, size_t ws_size,
                              hipStream_t stream) {
    const float* q   = (const float*)d_in[0];
    // d_in[1] = k — unused by the reference forward.
    const float* emb = (const float*)d_in[2];   // [4097, 64]
    float* out = (float*)d_out;                 // [2, 16, 2048, 2048]

    dim3 grid(32, 32);   // x: n-tile, y: bh
    dim3 block(256);
    shaw_rel_pos_kernel<<<grid, block, 0, stream>>>(q, emb, out);
}